// Round 2
// baseline (292.146 us; speedup 1.0000x reference)
//
#include <hip/hip_runtime.h>

// TNorm: out[b] = outer(g0, g1, g2, g3) flattened, g = x[b].reshape(4, 8).
// B=16384 rows, 32 inputs/row, 4096 outputs/row (fp32).
// Streaming floor: 256 MiB out + 2 MiB in -> ~42 us at the 6.4 TB/s the
// harness's own 1 GiB poison fill achieves (161 us, top dispatch every run).
//
// History:
//  R1 16384 blocks: 256 us. R2 2048 blocks x 8 rows: 254 us.
//  R3 nontemporal stores: EXACTLY neutral (dur/fill ratio 1.566 vs 1.567;
//    +10us was clock drift). Cache-policy lever does nothing.
// Model: dur = 161 us fill + ~93 us kernel window; 93 us = ~595 MB at wall
//   = our 258 MiB + ~330 MB leftover dirty poison (L3 256 + L2 32 MiB)
//   draining during our window. If true, kernel source cannot improve it.
//
// R4 (this): DISCRIMINATION PROBE — launch the identical kernel twice
// (idempotent, so correctness unchanged). Second launch runs with no poison
// drain: dur(2x) - dur(1x) = the kernel's clean standalone time.
//   ~45 us => kernel at BW wall, window is harness drain => roofline.
//   ~93 us => kernel intrinsically 2x off => real optimization target.
// Also reverts to R2's exact multiply order -> absmax back to 0.0.

#define ROW_IN 32
#define ROW_OUT 4096
#define ROWS_PER_BLOCK 8

typedef float f4 __attribute__((ext_vector_type(4)));

__global__ __launch_bounds__(256) void TNorm_71038759076547_kernel(
    const float* __restrict__ x, float* __restrict__ out) {
    __shared__ float g[ROWS_PER_BLOCK * ROW_IN];  // 1 KB

    const int t = threadIdx.x;
    const size_t row0 = (size_t)blockIdx.x * ROWS_PER_BLOCK;

    // Stage 8 rows (256 floats) with 64 float4 loads.
    if (t < ROWS_PER_BLOCK * (ROW_IN / 4)) {
        ((f4*)g)[t] = ((const f4*)(x + row0 * ROW_IN))[t];
    }
    __syncthreads();

    // Per-thread invariants: for element e = 4t + 1024i,
    //   j = ((t>>7) + 2i) & 7   (varies with i)
    //   k = (t>>4)&7, l = (t>>1)&7, g3-half = t&1  (invariant in i)
    const int kk   = (t >> 4) & 7;
    const int ll   = (t >> 1) & 7;
    const int half = t & 1;
    const int jb   = (t >> 7) & 7;

    f4* outbase = (f4*)out + row0 * (ROW_OUT / 4);

#pragma unroll
    for (int r = 0; r < ROWS_PER_BLOCK; ++r) {
        const float* gr = g + r * ROW_IN;
        const float g1k = gr[8 + kk];
        const float g2l = gr[16 + ll];
        const f4 gm = *(const f4*)(gr + 24 + 4 * half);

        f4* out4 = outbase + r * (ROW_OUT / 4);

#pragma unroll
        for (int i = 0; i < 4; ++i) {
            const int j = (jb + 2 * i) & 7;
            // R2-exact association: ((g0*g1)*g2) then s*gm -> absmax 0.
            const float s = gr[j] * g1k * g2l;
            f4 r4;
            r4.x = s * gm.x;
            r4.y = s * gm.y;
            r4.z = s * gm.z;
            r4.w = s * gm.w;
            out4[t + 256 * i] = r4;
        }
    }
}

extern "C" void kernel_launch(void* const* d_in, const int* in_sizes, int n_in,
                              void* d_out, int out_size, void* d_ws, size_t ws_size,
                              hipStream_t stream) {
    const float* x = (const float*)d_in[0];
    float* out = (float*)d_out;
    const int rows = in_sizes[0] / ROW_IN;            // 16384
    const int blocks = rows / ROWS_PER_BLOCK;         // 2048
    // Probe: two identical launches. Second is idempotent; its marginal cost
    // is the kernel's clean standalone duration (no poison-drain pollution).
    TNorm_71038759076547_kernel<<<blocks, 256, 0, stream>>>(x, out);
    TNorm_71038759076547_kernel<<<blocks, 256, 0, stream>>>(x, out);
}

// Round 3
// 253.367 us; speedup vs baseline: 1.1531x; 1.1531x over previous
//
#include <hip/hip_runtime.h>

// TNorm: out[b] = outer(g0, g1, g2, g3) flattened, g = x[b].reshape(4, 8).
// B=16384 rows, 32 inputs/row, 4096 outputs/row (fp32).
// Streaming floor: 256 MiB out + 2 MiB in -> ~39 us at the 6.6 TB/s the
// harness's own poison fills achieve.
//
// FINAL. Measured accounting of dur_us (~254 us):
//   161 us  1 GiB poison fill (harness, top dispatch every run)
//    41 us  256 MiB out-buffer poison fill (harness)
//    38 us  THIS KERNEL — measured via R4 double-launch probe
//           (dur 292.1 double vs 254.3 single => 37.8 us marginal),
//           i.e. at the HBM write wall (floor ~39 us).
//   ~10 us  launch gaps.
// R3 proved cache policy (nontemporal stores) is exactly neutral;
// R1/R2 proved block-shape is neutral. The ~216 us of harness traffic is
// not addressable from kernel source. Kernel is at roofline.

#define ROW_IN 32
#define ROW_OUT 4096
#define ROWS_PER_BLOCK 8

typedef float f4 __attribute__((ext_vector_type(4)));

__global__ __launch_bounds__(256) void TNorm_71038759076547_kernel(
    const float* __restrict__ x, float* __restrict__ out) {
    __shared__ float g[ROWS_PER_BLOCK * ROW_IN];  // 1 KB

    const int t = threadIdx.x;
    const size_t row0 = (size_t)blockIdx.x * ROWS_PER_BLOCK;

    // Stage 8 rows (256 floats) with 64 float4 loads.
    if (t < ROWS_PER_BLOCK * (ROW_IN / 4)) {
        ((f4*)g)[t] = ((const f4*)(x + row0 * ROW_IN))[t];
    }
    __syncthreads();

    // Per-thread invariants: for element e = 4t + 1024i,
    //   j = ((t>>7) + 2i) & 7   (varies with i)
    //   k = (t>>4)&7, l = (t>>1)&7, g3-half = t&1  (invariant in i)
    const int kk   = (t >> 4) & 7;
    const int ll   = (t >> 1) & 7;
    const int half = t & 1;
    const int jb   = (t >> 7) & 7;

    f4* outbase = (f4*)out + row0 * (ROW_OUT / 4);

#pragma unroll
    for (int r = 0; r < ROWS_PER_BLOCK; ++r) {
        const float* gr = g + r * ROW_IN;
        const float g1k = gr[8 + kk];
        const float g2l = gr[16 + ll];
        const f4 gm = *(const f4*)(gr + 24 + 4 * half);

        f4* out4 = outbase + r * (ROW_OUT / 4);

#pragma unroll
        for (int i = 0; i < 4; ++i) {
            const int j = (jb + 2 * i) & 7;
            // Reference-exact association: ((g0*g1)*g2) then s*gm -> absmax 0.
            const float s = gr[j] * g1k * g2l;
            f4 r4;
            r4.x = s * gm.x;
            r4.y = s * gm.y;
            r4.z = s * gm.z;
            r4.w = s * gm.w;
            out4[t + 256 * i] = r4;
        }
    }
}

extern "C" void kernel_launch(void* const* d_in, const int* in_sizes, int n_in,
                              void* d_out, int out_size, void* d_ws, size_t ws_size,
                              hipStream_t stream) {
    const float* x = (const float*)d_in[0];
    float* out = (float*)d_out;
    const int rows = in_sizes[0] / ROW_IN;            // 16384
    const int blocks = rows / ROWS_PER_BLOCK;         // 2048
    TNorm_71038759076547_kernel<<<blocks, 256, 0, stream>>>(x, out);
}